// Round 7
// baseline (158.350 us; speedup 1.0000x reference)
//
#include <hip/hip_runtime.h>

#define TPB 256
constexpr int B_ = 8, C_ = 192, H_ = 56, W_ = 56, O_ = 384;
constexpr int HW_ = H_ * W_;          // 3136
constexpr int NOFF = 18;              // 9 taps * 2 (dy,dx)
constexpr int NPIX = B_ * HW_;        // 25088 = 196 * 128

typedef __attribute__((ext_vector_type(8))) short short8v;
typedef __attribute__((ext_vector_type(4))) float f32x4;

__device__ inline unsigned short f2bf(float f) {
  unsigned u = __builtin_bit_cast(unsigned, f);
  unsigned r = (u + 0x7fffu + ((u >> 16) & 1u)) >> 16;
  return (unsigned short)r;
}
__device__ inline float bflo(unsigned u) {
  return __builtin_bit_cast(float, u << 16);
}
__device__ inline float bfhi(unsigned u) {
  return __builtin_bit_cast(float, u & 0xffff0000u);
}

// ---------------- K0: pw_w (O,C) fp32 -> bf16 same layout ----------------
__global__ __launch_bounds__(TPB) void k_wb(const float* __restrict__ pw,
                                            unsigned short* __restrict__ wtb) {
  int i = blockIdx.x * TPB + threadIdx.x;
  if (i < O_ * C_) wtb[i] = f2bf(pw[i]);
}

// ---------------- K1: depthwise 3x3, pad 1 (elementwise, full grid) -------
__global__ __launch_bounds__(TPB) void k_dw(const float* __restrict__ x,
                                            const float* __restrict__ wdw,
                                            float* __restrict__ t1) {
  int idx = blockIdx.x * TPB + threadIdx.x;
  if (idx >= B_ * C_ * HW_) return;
  int w = idx % W_;
  int h = (idx / W_) % H_;
  int c = (idx / HW_) % C_;
  const float* wp = wdw + c * 9;
  float acc = 0.f;
#pragma unroll
  for (int i = 0; i < 3; ++i) {
    int hh = h + i - 1;
    if ((unsigned)hh >= (unsigned)H_) continue;
#pragma unroll
    for (int j = 0; j < 3; ++j) {
      int ww = w + j - 1;
      if ((unsigned)ww >= (unsigned)W_) continue;
      acc += x[idx + (i - 1) * W_ + (j - 1)] * wp[i * 3 + j];
    }
  }
  t1[idx] = acc;
}

// ---------------- K2: pointwise C->18 + clip ----------------
__global__ __launch_bounds__(TPB) void k_pw18(const float* __restrict__ t1,
                                              const float* __restrict__ wpw,
                                              float* __restrict__ offp) {
  int idx = blockIdx.x * TPB + threadIdx.x;
  int q = idx % (HW_ / 4);
  int ch = (idx / (HW_ / 4)) % NOFF;
  int b = idx / (NOFF * (HW_ / 4));
  const float4* tp = (const float4*)(t1 + (size_t)b * C_ * HW_) + q;
  const float* wp = wpw + ch * C_;
  float4 acc = make_float4(0.f, 0.f, 0.f, 0.f);
  for (int c = 0; c < C_; ++c) {
    float4 v = tp[c * (HW_ / 4)];
    float wv = wp[c];
    acc.x += v.x * wv; acc.y += v.y * wv;
    acc.z += v.z * wv; acc.w += v.w * wv;
  }
  float4 r;
  r.x = fminf(fmaxf(acc.x, -1.f), 1.f);
  r.y = fminf(fmaxf(acc.y, -1.f), 1.f);
  r.z = fminf(fmaxf(acc.z, -1.f), 1.f);
  r.w = fminf(fmaxf(acc.w, -1.f), 1.f);
  float4* op = (float4*)(offp + ((size_t)b * NOFF + ch) * HW_) + q;
  *op = r;
}

// ---------------- K_XT: x[b][c][h][w] fp32 -> x_t[b][hw][c] bf16 ----------
__global__ __launch_bounds__(TPB) void k_xt(const float* __restrict__ x,
                                            unsigned short* __restrict__ xt) {
  __shared__ unsigned short tile[64 * 198];
  int tid = threadIdx.x;
  int P0 = blockIdx.x * 64;
  int b = blockIdx.y;
#pragma unroll
  for (int i = 0; i < 48; ++i) {
    int idx = i * TPB + tid;
    int px = idx & 63;
    int c = idx >> 6;
    float v = x[((size_t)(b * C_ + c)) * HW_ + P0 + px];
    tile[px * 198 + c] = f2bf(v);
  }
  __syncthreads();
  unsigned* xtu = (unsigned*)xt;
#pragma unroll
  for (int i = 0; i < 24; ++i) {
    int d = i * TPB + tid;            // dword index in 64*96
    int px = d / 96;
    int c2 = d - px * 96;
    unsigned v = *(const unsigned*)&tile[px * 198 + c2 * 2];
    xtu[((size_t)b * HW_ + P0 + px) * 96 + c2] = v;
  }
}

// ------- K3: deform sample + dcn; tap-split 3-way, partial f32 buffers ----
// 16 lanes/px, 12 ch/lane; blockIdx.y = tap-group (taps 3g..3g+2); each
// group writes its own y1p partial (no atomics, deterministic).
__global__ __launch_bounds__(TPB) void k_deform6(const unsigned short* __restrict__ xt,
                                                 const float* __restrict__ offp,
                                                 const float* __restrict__ dcn,
                                                 float* __restrict__ y1p) {
  __shared__ __align__(16) float dcnT[3 * C_];
  int tid = threadIdx.x;
  int kt0 = blockIdx.y * 3;
  for (int t = tid; t < 3 * C_; t += TPB) {
    int k = t / C_, c = t - k * C_;
    dcnT[t] = dcn[c * 9 + kt0 + k];
  }
  __syncthreads();
  y1p += (size_t)blockIdx.y * NPIX * C_;

  int px = blockIdx.x * 16 + (tid >> 4);
  int lg = tid & 15;
  int b = px / HW_;
  int hw = px - b * HW_;
  int h = hw / W_;
  int w = hw - h * W_;
  const float* op = offp + (size_t)b * NOFF * HW_ + hw;
  int pb = b * HW_;

  float acc[12];
#pragma unroll
  for (int j = 0; j < 12; ++j) acc[j] = 0.f;

#pragma unroll
  for (int k3 = 0; k3 < 3; ++k3) {
    int tap = kt0 + k3;
    int t3 = tap / 3;
    int ky = t3 - 1;
    int kx = tap - t3 * 3 - 1;
    float dy = op[(2 * tap) * HW_];
    float dx = op[(2 * tap + 1) * HW_];
    float ys = (float)(h + ky) + dy;
    float xs = (float)(w + kx) + dx;
    float y0f = floorf(ys), x0f = floorf(xs);
    float ty = ys - y0f, tx = xs - x0f;
    int y0 = (int)y0f, x0 = (int)x0f;
    int y1 = y0 + 1, x1 = x0 + 1;
    float fy0 = ((unsigned)y0 < (unsigned)H_) ? 1.f : 0.f;
    float fy1 = ((unsigned)y1 < (unsigned)H_) ? 1.f : 0.f;
    float fx0 = ((unsigned)x0 < (unsigned)W_) ? 1.f : 0.f;
    float fx1 = ((unsigned)x1 < (unsigned)W_) ? 1.f : 0.f;
    int y0c = y0 < 0 ? 0 : (y0 > H_ - 1 ? H_ - 1 : y0);
    int y1c = y1 < 0 ? 0 : (y1 > H_ - 1 ? H_ - 1 : y1);
    int x0c = x0 < 0 ? 0 : (x0 > W_ - 1 ? W_ - 1 : x0);
    int x1c = x1 < 0 ? 0 : (x1 > W_ - 1 ? W_ - 1 : x1);
    float omty = 1.f - ty, omtx = 1.f - tx;
    float w00 = omty * omtx * fy0 * fx0;
    float w01 = omty * tx * fy0 * fx1;
    float w10 = ty * omtx * fy1 * fx0;
    float w11 = ty * tx * fy1 * fx1;
    int r0 = (pb + y0c * W_) * C_;
    int r1 = (pb + y1c * W_) * C_;
    int p00 = r0 + x0c * C_;
    int p01 = r0 + x1c * C_;
    int p10 = r1 + x0c * C_;
    int p11 = r1 + x1c * C_;
#pragma unroll
    for (int rep = 0; rep < 3; ++rep) {
      int c0 = lg * 4 + rep * 64;
      uint2 u00 = *(const uint2*)(xt + p00 + c0);
      uint2 u01 = *(const uint2*)(xt + p01 + c0);
      uint2 u10 = *(const uint2*)(xt + p10 + c0);
      uint2 u11 = *(const uint2*)(xt + p11 + c0);
      f32x4 dw = *(const f32x4*)&dcnT[k3 * C_ + c0];
      float s0 = w00 * bflo(u00.x) + w01 * bflo(u01.x) + w10 * bflo(u10.x) + w11 * bflo(u11.x);
      float s1 = w00 * bfhi(u00.x) + w01 * bfhi(u01.x) + w10 * bfhi(u10.x) + w11 * bfhi(u11.x);
      float s2 = w00 * bflo(u00.y) + w01 * bflo(u01.y) + w10 * bflo(u10.y) + w11 * bflo(u11.y);
      float s3 = w00 * bfhi(u00.y) + w01 * bfhi(u01.y) + w10 * bfhi(u10.y) + w11 * bfhi(u11.y);
      acc[rep * 4 + 0] += s0 * dw.x;
      acc[rep * 4 + 1] += s1 * dw.y;
      acc[rep * 4 + 2] += s2 * dw.z;
      acc[rep * 4 + 3] += s3 * dw.w;
    }
  }

  int ob = px * C_ + lg * 4;
#pragma unroll
  for (int rep = 0; rep < 3; ++rep) {
    float4 v;
    v.x = acc[rep * 4 + 0];
    v.y = acc[rep * 4 + 1];
    v.z = acc[rep * 4 + 2];
    v.w = acc[rep * 4 + 3];
    *(float4*)(y1p + ob + rep * 64) = v;
  }
}

// ---- K4: MFMA bf16 GEMM; stage = sum 3 f32 partials -> bf16 swizzled LDS -
__global__ __launch_bounds__(TPB) void k_gemm2f(const float* __restrict__ y1p,
                                                const unsigned short* __restrict__ wtb,
                                                float* __restrict__ out) {
  __shared__ __align__(16) unsigned short bsm[128 * 192];  // 48 KB
  int tid = threadIdx.x;
  int n0 = blockIdx.x * 128;
  int m0 = blockIdx.y * 64;

  const float* s0 = y1p + (size_t)n0 * C_;
  const float* s1 = s0 + (size_t)NPIX * C_;
  const float* s2 = s1 + (size_t)NPIX * C_;
  char* sbase = (char*)bsm;
#pragma unroll
  for (int i = 0; i < 24; ++i) {
    int u = i * TPB + tid;            // 8B-dst unit: 128 rows x 48 units
    int row = u / 48;
    int cu = u - row * 48;
    int so = row * 192 + cu * 4;
    float4 a = *(const float4*)(s0 + so);
    float4 b4 = *(const float4*)(s1 + so);
    float4 c4 = *(const float4*)(s2 + so);
    float v0 = a.x + b4.x + c4.x;
    float v1 = a.y + b4.y + c4.y;
    float v2 = a.z + b4.z + c4.z;
    float v3 = a.w + b4.w + c4.w;
    uint2 pk;
    pk.x = (unsigned)f2bf(v0) | ((unsigned)f2bf(v1) << 16);
    pk.y = (unsigned)f2bf(v2) | ((unsigned)f2bf(v3) << 16);
    *(uint2*)(sbase + row * 384 + ((cu * 8) ^ ((row & 7) << 4))) = pk;
  }
  __syncthreads();

  int wid = tid >> 6;
  int lane = tid & 63;
  int col = lane & 15;
  int kg = lane >> 4;

  f32x4 acc[4][2];
#pragma unroll
  for (int mf = 0; mf < 4; ++mf)
#pragma unroll
    for (int nf = 0; nf < 2; ++nf) acc[mf][nf] = (f32x4){0.f, 0.f, 0.f, 0.f};

#pragma unroll
  for (int k0 = 0; k0 < C_; k0 += 32) {
    short8v a[4], bfr[2];
#pragma unroll
    for (int mf = 0; mf < 4; ++mf)
      a[mf] = *(const short8v*)(wtb + (m0 + mf * 16 + col) * C_ + k0 + kg * 8);
#pragma unroll
    for (int nf = 0; nf < 2; ++nf) {
      int brow = wid * 32 + nf * 16 + col;
      int kb = (k0 + kg * 8) * 2;
      bfr[nf] = *(const short8v*)(sbase + brow * 384 + (kb ^ ((brow & 7) << 4)));
    }
#pragma unroll
    for (int mf = 0; mf < 4; ++mf)
#pragma unroll
      for (int nf = 0; nf < 2; ++nf)
        acc[mf][nf] = __builtin_amdgcn_mfma_f32_16x16x32_bf16(a[mf], bfr[nf], acc[mf][nf], 0, 0, 0);
  }

#pragma unroll
  for (int mf = 0; mf < 4; ++mf) {
#pragma unroll
    for (int nf = 0; nf < 2; ++nf) {
      int p = n0 + wid * 32 + nf * 16 + col;
      int bb = p / HW_;
      int hw = p - bb * HW_;
#pragma unroll
      for (int reg = 0; reg < 4; ++reg) {
        int o = m0 + mf * 16 + kg * 4 + reg;
        float a = acc[mf][nf][reg];
        float r = a * fminf(fmaxf(a + 3.f, 0.f), 6.f) * (1.f / 6.f);
        out[((size_t)bb * O_ + o) * HW_ + hw] = r;
      }
    }
  }
}

extern "C" void kernel_launch(void* const* d_in, const int* in_sizes, int n_in,
                              void* d_out, int out_size, void* d_ws, size_t ws_size,
                              hipStream_t stream) {
  const float* x = (const float*)d_in[0];
  const float* og_dw = (const float*)d_in[1];
  const float* og_pw = (const float*)d_in[2];
  const float* dcn_w = (const float*)d_in[3];
  const float* pw_w = (const float*)d_in[4];
  float* out = (float*)d_out;

  float* ws = (float*)d_ws;
  float* t1 = ws;                                        // B*C*HW fp32
  float* offp = t1 + (size_t)B_ * C_ * HW_;              // B*18*HW fp32
  float* y1p = offp + (size_t)B_ * NOFF * HW_;           // 3 * NPIX*C fp32
  unsigned short* wtb = (unsigned short*)(y1p + 3 * (size_t)NPIX * C_);
  unsigned short* x_t = wtb + (size_t)O_ * C_;           // NPIX*C bf16

  k_wb<<<(O_ * C_ + TPB - 1) / TPB, TPB, 0, stream>>>(pw_w, wtb);
  k_dw<<<(B_ * C_ * HW_ + TPB - 1) / TPB, TPB, 0, stream>>>(x, og_dw, t1);
  k_xt<<<dim3(HW_ / 64, B_), TPB, 0, stream>>>(x, x_t);
  k_pw18<<<(B_ * NOFF * (HW_ / 4)) / TPB, TPB, 0, stream>>>(t1, og_pw, offp);
  k_deform6<<<dim3(NPIX / 16, 3), TPB, 0, stream>>>(x_t, offp, dcn_w, y1p);
  k_gemm2f<<<dim3(NPIX / 128, O_ / 64), TPB, 0, stream>>>(y1p, wtb, out);
}

// Round 8
// 131.350 us; speedup vs baseline: 1.2056x; 1.2056x over previous
//
#include <hip/hip_runtime.h>

#define TPB 256
constexpr int B_ = 8, C_ = 192, H_ = 56, W_ = 56, O_ = 384;
constexpr int HW_ = H_ * W_;          // 3136
constexpr int NOFF = 18;              // 9 taps * 2 (dy,dx)
constexpr int NPIX = B_ * HW_;        // 25088 = 196 * 128

typedef __attribute__((ext_vector_type(8))) short short8v;
typedef __attribute__((ext_vector_type(4))) float f32x4;

__device__ inline unsigned short f2bf(float f) {
  unsigned u = __builtin_bit_cast(unsigned, f);
  unsigned r = (u + 0x7fffu + ((u >> 16) & 1u)) >> 16;
  return (unsigned short)r;
}
__device__ inline float bflo(unsigned u) {
  return __builtin_bit_cast(float, u << 16);
}
__device__ inline float bfhi(unsigned u) {
  return __builtin_bit_cast(float, u & 0xffff0000u);
}

// ---------------- K0: pw_w (O,C) fp32 -> bf16 same layout ----------------
__global__ __launch_bounds__(TPB) void k_wb(const float* __restrict__ pw,
                                            unsigned short* __restrict__ wtb) {
  int i = blockIdx.x * TPB + threadIdx.x;
  if (i < O_ * C_) wtb[i] = f2bf(pw[i]);
}

// ---------------- K1: depthwise 3x3, pad 1 (elementwise, full grid) -------
__global__ __launch_bounds__(TPB) void k_dw(const float* __restrict__ x,
                                            const float* __restrict__ wdw,
                                            float* __restrict__ t1) {
  int idx = blockIdx.x * TPB + threadIdx.x;
  if (idx >= B_ * C_ * HW_) return;
  int w = idx % W_;
  int h = (idx / W_) % H_;
  int c = (idx / HW_) % C_;
  const float* wp = wdw + c * 9;
  float acc = 0.f;
#pragma unroll
  for (int i = 0; i < 3; ++i) {
    int hh = h + i - 1;
    if ((unsigned)hh >= (unsigned)H_) continue;
#pragma unroll
    for (int j = 0; j < 3; ++j) {
      int ww = w + j - 1;
      if ((unsigned)ww >= (unsigned)W_) continue;
      acc += x[idx + (i - 1) * W_ + (j - 1)] * wp[i * 3 + j];
    }
  }
  t1[idx] = acc;
}

// ---------------- K2: pointwise C->18 + clip ----------------
__global__ __launch_bounds__(TPB) void k_pw18(const float* __restrict__ t1,
                                              const float* __restrict__ wpw,
                                              float* __restrict__ offp) {
  int idx = blockIdx.x * TPB + threadIdx.x;
  int q = idx % (HW_ / 4);
  int ch = (idx / (HW_ / 4)) % NOFF;
  int b = idx / (NOFF * (HW_ / 4));
  const float4* tp = (const float4*)(t1 + (size_t)b * C_ * HW_) + q;
  const float* wp = wpw + ch * C_;
  float4 acc = make_float4(0.f, 0.f, 0.f, 0.f);
  for (int c = 0; c < C_; ++c) {
    float4 v = tp[c * (HW_ / 4)];
    float wv = wp[c];
    acc.x += v.x * wv; acc.y += v.y * wv;
    acc.z += v.z * wv; acc.w += v.w * wv;
  }
  float4 r;
  r.x = fminf(fmaxf(acc.x, -1.f), 1.f);
  r.y = fminf(fmaxf(acc.y, -1.f), 1.f);
  r.z = fminf(fmaxf(acc.z, -1.f), 1.f);
  r.w = fminf(fmaxf(acc.w, -1.f), 1.f);
  float4* op = (float4*)(offp + ((size_t)b * NOFF + ch) * HW_) + q;
  *op = r;
}

// ---------------- K_XT: x[b][c][h][w] fp32 -> x_t[b][hw][c] bf16 ----------
__global__ __launch_bounds__(TPB) void k_xt(const float* __restrict__ x,
                                            unsigned short* __restrict__ xt) {
  __shared__ unsigned short tile[64 * 198];
  int tid = threadIdx.x;
  int P0 = blockIdx.x * 64;
  int b = blockIdx.y;
#pragma unroll
  for (int i = 0; i < 48; ++i) {
    int idx = i * TPB + tid;
    int px = idx & 63;
    int c = idx >> 6;
    float v = x[((size_t)(b * C_ + c)) * HW_ + P0 + px];
    tile[px * 198 + c] = f2bf(v);
  }
  __syncthreads();
  unsigned* xtu = (unsigned*)xt;
#pragma unroll
  for (int i = 0; i < 24; ++i) {
    int d = i * TPB + tid;            // dword index in 64*96
    int px = d / 96;
    int c2 = d - px * 96;
    unsigned v = *(const unsigned*)&tile[px * 198 + c2 * 2];
    xtu[((size_t)b * HW_ + P0 + px) * 96 + c2] = v;
  }
}

// ------- K3: deform sample + dcn; tap-split 3-way, partial f32 buffers ----
__global__ __launch_bounds__(TPB) void k_deform6(const unsigned short* __restrict__ xt,
                                                 const float* __restrict__ offp,
                                                 const float* __restrict__ dcn,
                                                 float* __restrict__ y1p) {
  __shared__ __align__(16) float dcnT[3 * C_];
  int tid = threadIdx.x;
  int kt0 = blockIdx.y * 3;
  for (int t = tid; t < 3 * C_; t += TPB) {
    int k = t / C_, c = t - k * C_;
    dcnT[t] = dcn[c * 9 + kt0 + k];
  }
  __syncthreads();
  y1p += (size_t)blockIdx.y * NPIX * C_;

  int px = blockIdx.x * 16 + (tid >> 4);
  int lg = tid & 15;
  int b = px / HW_;
  int hw = px - b * HW_;
  int h = hw / W_;
  int w = hw - h * W_;
  const float* op = offp + (size_t)b * NOFF * HW_ + hw;
  int pb = b * HW_;

  float acc[12];
#pragma unroll
  for (int j = 0; j < 12; ++j) acc[j] = 0.f;

#pragma unroll
  for (int k3 = 0; k3 < 3; ++k3) {
    int tap = kt0 + k3;
    int t3 = tap / 3;
    int ky = t3 - 1;
    int kx = tap - t3 * 3 - 1;
    float dy = op[(2 * tap) * HW_];
    float dx = op[(2 * tap + 1) * HW_];
    float ys = (float)(h + ky) + dy;
    float xs = (float)(w + kx) + dx;
    float y0f = floorf(ys), x0f = floorf(xs);
    float ty = ys - y0f, tx = xs - x0f;
    int y0 = (int)y0f, x0 = (int)x0f;
    int y1 = y0 + 1, x1 = x0 + 1;
    float fy0 = ((unsigned)y0 < (unsigned)H_) ? 1.f : 0.f;
    float fy1 = ((unsigned)y1 < (unsigned)H_) ? 1.f : 0.f;
    float fx0 = ((unsigned)x0 < (unsigned)W_) ? 1.f : 0.f;
    float fx1 = ((unsigned)x1 < (unsigned)W_) ? 1.f : 0.f;
    int y0c = y0 < 0 ? 0 : (y0 > H_ - 1 ? H_ - 1 : y0);
    int y1c = y1 < 0 ? 0 : (y1 > H_ - 1 ? H_ - 1 : y1);
    int x0c = x0 < 0 ? 0 : (x0 > W_ - 1 ? W_ - 1 : x0);
    int x1c = x1 < 0 ? 0 : (x1 > W_ - 1 ? W_ - 1 : x1);
    float omty = 1.f - ty, omtx = 1.f - tx;
    float w00 = omty * omtx * fy0 * fx0;
    float w01 = omty * tx * fy0 * fx1;
    float w10 = ty * omtx * fy1 * fx0;
    float w11 = ty * tx * fy1 * fx1;
    int r0 = (pb + y0c * W_) * C_;
    int r1 = (pb + y1c * W_) * C_;
    int p00 = r0 + x0c * C_;
    int p01 = r0 + x1c * C_;
    int p10 = r1 + x0c * C_;
    int p11 = r1 + x1c * C_;
#pragma unroll
    for (int rep = 0; rep < 3; ++rep) {
      int c0 = lg * 4 + rep * 64;
      uint2 u00 = *(const uint2*)(xt + p00 + c0);
      uint2 u01 = *(const uint2*)(xt + p01 + c0);
      uint2 u10 = *(const uint2*)(xt + p10 + c0);
      uint2 u11 = *(const uint2*)(xt + p11 + c0);
      f32x4 dw = *(const f32x4*)&dcnT[k3 * C_ + c0];
      float s0 = w00 * bflo(u00.x) + w01 * bflo(u01.x) + w10 * bflo(u10.x) + w11 * bflo(u11.x);
      float s1 = w00 * bfhi(u00.x) + w01 * bfhi(u01.x) + w10 * bfhi(u10.x) + w11 * bfhi(u11.x);
      float s2 = w00 * bflo(u00.y) + w01 * bflo(u01.y) + w10 * bflo(u10.y) + w11 * bflo(u11.y);
      float s3 = w00 * bfhi(u00.y) + w01 * bfhi(u01.y) + w10 * bfhi(u10.y) + w11 * bfhi(u11.y);
      acc[rep * 4 + 0] += s0 * dw.x;
      acc[rep * 4 + 1] += s1 * dw.y;
      acc[rep * 4 + 2] += s2 * dw.z;
      acc[rep * 4 + 3] += s3 * dw.w;
    }
  }

  int ob = px * C_ + lg * 4;
#pragma unroll
  for (int rep = 0; rep < 3; ++rep) {
    float4 v;
    v.x = acc[rep * 4 + 0];
    v.y = acc[rep * 4 + 1];
    v.z = acc[rep * 4 + 2];
    v.w = acc[rep * 4 + 3];
    *(float4*)(y1p + ob + rep * 64) = v;
  }
}

// ---- K4: one block = 64 px x ALL 384 O; partials read ONCE, m-loop over LDS
__global__ __launch_bounds__(TPB) void k_gemm3(const float* __restrict__ y1p,
                                               const unsigned short* __restrict__ wtb,
                                               float* __restrict__ out) {
  __shared__ __align__(16) unsigned short bsm[64 * 192];  // 24 KB
  int tid = threadIdx.x;
  int n0 = blockIdx.x * 64;

  // stage: sum 3 f32 partials -> bf16 -> swizzled LDS (read once per block)
  const float* s0 = y1p + (size_t)n0 * C_;
  const float* s1 = s0 + (size_t)NPIX * C_;
  const float* s2 = s1 + (size_t)NPIX * C_;
  char* sbase = (char*)bsm;
#pragma unroll
  for (int i = 0; i < 12; ++i) {
    int u = i * TPB + tid;            // 8B-dst unit: 64 rows x 48 units
    int row = u / 48;
    int cu = u - row * 48;
    int so = row * 192 + cu * 4;
    float4 a = *(const float4*)(s0 + so);
    float4 b4 = *(const float4*)(s1 + so);
    float4 c4 = *(const float4*)(s2 + so);
    float v0 = a.x + b4.x + c4.x;
    float v1 = a.y + b4.y + c4.y;
    float v2 = a.z + b4.z + c4.z;
    float v3 = a.w + b4.w + c4.w;
    uint2 pk;
    pk.x = (unsigned)f2bf(v0) | ((unsigned)f2bf(v1) << 16);
    pk.y = (unsigned)f2bf(v2) | ((unsigned)f2bf(v3) << 16);
    *(uint2*)(sbase + row * 384 + ((cu * 8) ^ ((row & 7) << 4))) = pk;
  }
  __syncthreads();

  int wid = tid >> 6;
  int lane = tid & 63;
  int col = lane & 15;
  int kg = lane >> 4;
  int wr = wid >> 1;                  // O-half (0,1)
  int wc = wid & 1;                   // px-half (0,1)

#pragma unroll 1
  for (int m0 = 0; m0 < O_; m0 += 64) {
    f32x4 acc[2][2];
#pragma unroll
    for (int mf = 0; mf < 2; ++mf)
#pragma unroll
      for (int nf = 0; nf < 2; ++nf) acc[mf][nf] = (f32x4){0.f, 0.f, 0.f, 0.f};

#pragma unroll
    for (int k0 = 0; k0 < C_; k0 += 32) {
      short8v a[2], bfr[2];
#pragma unroll
      for (int mf = 0; mf < 2; ++mf)
        a[mf] = *(const short8v*)(wtb + (m0 + wr * 32 + mf * 16 + col) * C_ + k0 + kg * 8);
#pragma unroll
      for (int nf = 0; nf < 2; ++nf) {
        int brow = wc * 32 + nf * 16 + col;
        int kb = (k0 + kg * 8) * 2;
        bfr[nf] = *(const short8v*)(sbase + brow * 384 + (kb ^ ((brow & 7) << 4)));
      }
#pragma unroll
      for (int mf = 0; mf < 2; ++mf)
#pragma unroll
        for (int nf = 0; nf < 2; ++nf)
          acc[mf][nf] = __builtin_amdgcn_mfma_f32_16x16x32_bf16(a[mf], bfr[nf], acc[mf][nf], 0, 0, 0);
    }

#pragma unroll
    for (int mf = 0; mf < 2; ++mf) {
#pragma unroll
      for (int nf = 0; nf < 2; ++nf) {
        int p = n0 + wc * 32 + nf * 16 + col;
        int bb = p / HW_;
        int hw = p - bb * HW_;
#pragma unroll
        for (int reg = 0; reg < 4; ++reg) {
          int o = m0 + wr * 32 + mf * 16 + kg * 4 + reg;
          float a = acc[mf][nf][reg];
          float r = a * fminf(fmaxf(a + 3.f, 0.f), 6.f) * (1.f / 6.f);
          out[((size_t)bb * O_ + o) * HW_ + hw] = r;
        }
      }
    }
  }
}

extern "C" void kernel_launch(void* const* d_in, const int* in_sizes, int n_in,
                              void* d_out, int out_size, void* d_ws, size_t ws_size,
                              hipStream_t stream) {
  const float* x = (const float*)d_in[0];
  const float* og_dw = (const float*)d_in[1];
  const float* og_pw = (const float*)d_in[2];
  const float* dcn_w = (const float*)d_in[3];
  const float* pw_w = (const float*)d_in[4];
  float* out = (float*)d_out;

  float* ws = (float*)d_ws;
  float* t1 = ws;                                        // B*C*HW fp32
  float* offp = t1 + (size_t)B_ * C_ * HW_;              // B*18*HW fp32
  float* y1p = offp + (size_t)B_ * NOFF * HW_;           // 3 * NPIX*C fp32
  unsigned short* wtb = (unsigned short*)(y1p + 3 * (size_t)NPIX * C_);
  unsigned short* x_t = wtb + (size_t)O_ * C_;           // NPIX*C bf16

  k_wb<<<(O_ * C_ + TPB - 1) / TPB, TPB, 0, stream>>>(pw_w, wtb);
  k_dw<<<(B_ * C_ * HW_ + TPB - 1) / TPB, TPB, 0, stream>>>(x, og_dw, t1);
  k_xt<<<dim3(HW_ / 64, B_), TPB, 0, stream>>>(x, x_t);
  k_pw18<<<(B_ * NOFF * (HW_ / 4)) / TPB, TPB, 0, stream>>>(t1, og_pw, offp);
  k_deform6<<<dim3(NPIX / 16, 3), TPB, 0, stream>>>(x_t, offp, dcn_w, y1p);
  k_gemm3<<<NPIX / 64, TPB, 0, stream>>>(y1p, wtb, out);
}